// Round 5
// baseline (242.142 us; speedup 1.0000x reference)
//
#include <hip/hip_runtime.h>

#define N_NODES 10000
#define N_EDGES 160000
#define FNODE 8
#define FEDGE 4
#define C 24
#define NITER 4
#define HID 16
#define NB_HEAD 60

// All scratch lives in module-owned device globals: immune to d_ws poisoning
// and to any ws_size limit. Re-initialized (or fully overwritten) every call.
__device__ float    g_hA[N_NODES * C];
__device__ float    g_hB[N_NODES * C];
__device__ unsigned g_agg[N_NODES * C];
__device__ float    g_partial[NB_HEAD * HID];

// Monotone float <-> uint mapping: unsigned compare == float total order.
// fenc(f) > 0 for every finite/inf f, so 0u is a safe "empty segment" sentinel.
__device__ __forceinline__ unsigned fenc(float f) {
    unsigned u = __float_as_uint(f);
    return (u & 0x80000000u) ? ~u : (u | 0x80000000u);
}
__device__ __forceinline__ float fdec(unsigned u) {
    unsigned v = (u & 0x80000000u) ? (u & 0x7FFFFFFFu) : ~u;
    return __uint_as_float(v);
}

__global__ void zero_agg_kernel() {
    const int t = blockIdx.x * blockDim.x + threadIdx.x;
    if (t < N_NODES * C) g_agg[t] = 0u;
}

// One thread per (edge, out_channel). blockDim = (C, EPB).
// W: [FEDGE][IN_C*C] row-major, b: [IN_C*C]; w[e][i][o] = b[i*C+o] + sum_f ea[e][f]*W[f][i*C+o]
// msg[e][o] = sum_i h[src[e]][i] * w[e][i][o];  atomicMax into agg[dst[e]*C+o].
template <int IN_C, int EPB>
__global__ void edge_kernel(const float* __restrict__ h,
                            const float* __restrict__ ea,
                            const int* __restrict__ src,
                            const int* __restrict__ dst,
                            const float* __restrict__ W,
                            const float* __restrict__ b,
                            unsigned* __restrict__ agg) {
    __shared__ float sW[5 * IN_C * C];   // [f=0..3: W, f=4: bias]
    __shared__ float sh[EPB * IN_C];

    const int tid = threadIdx.x + threadIdx.y * C;
    const int nthr = C * EPB;
    for (int idx = tid; idx < 5 * IN_C * C; idx += nthr)
        sW[idx] = (idx < 4 * IN_C * C) ? W[idx] : b[idx - 4 * IN_C * C];

    const int e = blockIdx.x * EPB + threadIdx.y;
    if (e < N_EDGES) {
        if (threadIdx.x < IN_C) {
            const int s = src[e];
            sh[threadIdx.y * IN_C + threadIdx.x] = h[s * IN_C + threadIdx.x];
        }
    }
    __syncthreads();
    if (e >= N_EDGES) return;

    const int o = threadIdx.x;
    const float a0 = ea[e * 4 + 0];
    const float a1 = ea[e * 4 + 1];
    const float a2 = ea[e * 4 + 2];
    const float a3 = ea[e * 4 + 3];
    const float* hs = &sh[threadIdx.y * IN_C];

    float acc = 0.f;
#pragma unroll
    for (int i = 0; i < IN_C; ++i) {
        float w = sW[4 * IN_C * C + i * C + o];
        w = fmaf(a0, sW[0 * IN_C * C + i * C + o], w);
        w = fmaf(a1, sW[1 * IN_C * C + i * C + o], w);
        w = fmaf(a2, sW[2 * IN_C * C + i * C + o], w);
        w = fmaf(a3, sW[3 * IN_C * C + i * C + o], w);
        acc = fmaf(hs[i], w, acc);
    }
    atomicMax(&agg[dst[e] * C + o], fenc(acc));
}

// One thread per (node, out_channel): h_out = relu6(agg_or_0 + h_in @ root + bias).
// Also resets agg to 0 (each element exactly once -> clean for next layer).
template <int IN_C>
__global__ void node_kernel(const float* __restrict__ h_in,
                            unsigned* __restrict__ agg,
                            const float* __restrict__ root,  // [IN_C][C]
                            const float* __restrict__ bias,  // [C]
                            float* __restrict__ h_out) {
    const int t = blockIdx.x * blockDim.x + threadIdx.x;
    if (t >= N_NODES * C) return;
    const int n = t / C;
    const int o = t - n * C;
    const unsigned u = agg[t];
    agg[t] = 0u;
    float acc = (u == 0u ? 0.f : fdec(u)) + bias[o];
#pragma unroll
    for (int i = 0; i < IN_C; ++i)
        acc = fmaf(h_in[n * IN_C + i], root[i * C + o], acc);
    h_out[t] = fminf(fmaxf(acc, 0.f), 6.f);
}

// Stage 1 of head GEMV: per-block partial sums for the 16 hidden units (deterministic).
__global__ void head1_kernel(const float* __restrict__ h,     // [N*C]
                             const float* __restrict__ w1,    // [N*C][HID]
                             float* __restrict__ partial) {   // [NB_HEAD][HID]
    __shared__ float s[256 * HID];
    float acc[HID];
#pragma unroll
    for (int j = 0; j < HID; ++j) acc[j] = 0.f;

    for (int k = blockIdx.x * blockDim.x + threadIdx.x; k < N_NODES * C;
         k += gridDim.x * blockDim.x) {
        const float f = h[k];
        const float4* wp = (const float4*)(w1 + (size_t)k * HID);
#pragma unroll
        for (int q = 0; q < 4; ++q) {
            const float4 w = wp[q];
            acc[q * 4 + 0] = fmaf(f, w.x, acc[q * 4 + 0]);
            acc[q * 4 + 1] = fmaf(f, w.y, acc[q * 4 + 1]);
            acc[q * 4 + 2] = fmaf(f, w.z, acc[q * 4 + 2]);
            acc[q * 4 + 3] = fmaf(f, w.w, acc[q * 4 + 3]);
        }
    }
#pragma unroll
    for (int j = 0; j < HID; ++j) s[threadIdx.x * HID + j] = acc[j];
    __syncthreads();
    for (int off = 128; off > 0; off >>= 1) {
        if (threadIdx.x < off) {
#pragma unroll
            for (int j = 0; j < HID; ++j)
                s[threadIdx.x * HID + j] += s[(threadIdx.x + off) * HID + j];
        }
        __syncthreads();
    }
    if (threadIdx.x < HID) partial[blockIdx.x * HID + threadIdx.x] = s[threadIdx.x];
}

// Stage 2: reduce partials in fixed order, ELU, 16-dot, ELU -> scalar out.
__global__ void head2_kernel(const float* __restrict__ partial,
                             const float* __restrict__ b1,
                             const float* __restrict__ w2,
                             const float* __restrict__ b2,
                             float* __restrict__ out) {
    __shared__ float hid[HID];
    const int j = threadIdx.x;
    if (j < HID) {
        float a = b1[j];
        for (int bidx = 0; bidx < NB_HEAD; ++bidx) a += partial[bidx * HID + j];
        hid[j] = (a > 0.f) ? a : expm1f(a);
    }
    __syncthreads();
    if (j == 0) {
        float a = b2[0];
#pragma unroll
        for (int q = 0; q < HID; ++q) a += hid[q] * w2[q];
        out[0] = (a > 0.f) ? a : expm1f(a);
    }
}

extern "C" void kernel_launch(void* const* d_in, const int* in_sizes, int n_in,
                              void* d_out, int out_size, void* d_ws, size_t ws_size,
                              hipStream_t stream) {
    const float* x      = (const float*)d_in[0];   // [N][FNODE]
    const float* ea     = (const float*)d_in[1];   // [E][FEDGE]
    const int*   ei     = (const int*)d_in[2];     // [2][E]
    const float* few    = (const float*)d_in[3];   // [FEDGE][FNODE*C]
    const float* feb    = (const float*)d_in[4];   // [FNODE*C]
    const float* ew     = (const float*)d_in[5];   // [FEDGE][C*C]
    const float* ebias  = (const float*)d_in[6];   // [C*C]
    const float* root0  = (const float*)d_in[7];   // [FNODE][C]
    const float* bias0  = (const float*)d_in[8];   // [C]
    const float* roots  = (const float*)d_in[9];   // [NITER][C][C]
    const float* biases = (const float*)d_in[10];  // [NITER][C]
    const float* w1     = (const float*)d_in[11];  // [N*C][HID]
    const float* b1     = (const float*)d_in[12];  // [HID]
    const float* w2     = (const float*)d_in[13];  // [HID]
    const float* b2     = (const float*)d_in[14];  // [1]
    float* out = (float*)d_out;

    const int* src = ei;
    const int* dst = ei + N_EDGES;

    // Resolve device-global scratch addresses (host-side query; capture-safe).
    void *pA_, *pB_, *pAgg_, *pPart_;
    hipGetSymbolAddress(&pA_,   HIP_SYMBOL(g_hA));
    hipGetSymbolAddress(&pB_,   HIP_SYMBOL(g_hB));
    hipGetSymbolAddress(&pAgg_, HIP_SYMBOL(g_agg));
    hipGetSymbolAddress(&pPart_,HIP_SYMBOL(g_partial));
    float*    hA      = (float*)pA_;
    float*    hB      = (float*)pB_;
    unsigned* agg     = (unsigned*)pAgg_;
    float*    partial = (float*)pPart_;

    constexpr int EPB = 16;
    dim3 eblk(C, EPB);
    const int egrid = (N_EDGES + EPB - 1) / EPB;
    const int ngrid = (N_NODES * C + 255) / 256;

    zero_agg_kernel<<<ngrid, 256, 0, stream>>>();

    // Layer 0: x [N,8] -> hA [N,24]
    edge_kernel<FNODE, EPB><<<egrid, eblk, 0, stream>>>(x, ea, src, dst, few, feb, agg);
    node_kernel<FNODE><<<ngrid, 256, 0, stream>>>(x, agg, root0, bias0, hA);

    float* cur = hA;
    float* nxt = hB;
    for (int i = 0; i < NITER; ++i) {
        edge_kernel<C, EPB><<<egrid, eblk, 0, stream>>>(cur, ea, src, dst, ew, ebias, agg);
        node_kernel<C><<<ngrid, 256, 0, stream>>>(cur, agg, roots + i * C * C,
                                                  biases + i * C, nxt);
        float* t = cur; cur = nxt; nxt = t;
    }

    head1_kernel<<<NB_HEAD, 256, 0, stream>>>(cur, w1, partial);
    head2_kernel<<<1, 64, 0, stream>>>(partial, b1, w2, b2, out);
}

// Round 6
// 214.473 us; speedup vs baseline: 1.1290x; 1.1290x over previous
//
#include <hip/hip_runtime.h>

#define N_NODES 10000
#define N_EDGES 160000
#define FNODE 8
#define FEDGE 4
#define C 24
#define NITER 4
#define HID 16
#define NB_HEAD 60
#define TW (5 * C)   // 120: per-node T row = [f=0..3: ea-weighted][f=4: bias part]

// Module-owned scratch: immune to d_ws poisoning / ws_size limits.
__device__ float    g_hA[N_NODES * C];
__device__ float    g_hB[N_NODES * C];
__device__ unsigned g_agg[N_NODES * C];
__device__ float    g_T[N_NODES * TW];
__device__ float    g_partial[NB_HEAD * HID];

// Monotone float <-> uint mapping: unsigned compare == float total order.
// fenc(f) > 0 for all finite f, so 0u is a safe "empty segment" sentinel.
__device__ __forceinline__ unsigned fenc(float f) {
    unsigned u = __float_as_uint(f);
    return (u & 0x80000000u) ? ~u : (u | 0x80000000u);
}
__device__ __forceinline__ float fdec(unsigned u) {
    unsigned v = (u & 0x80000000u) ? (u & 0x7FFFFFFFu) : ~u;
    return __uint_as_float(v);
}

__global__ void zero_agg_kernel() {
    const int t = blockIdx.x * blockDim.x + threadIdx.x;
    if (t < N_NODES * C) g_agg[t] = 0u;
}

// Per-node weight projection: T[n][f*C+o] = sum_i h[n][i]*W[f][i*C+o] (f<4),
// T[n][4*C+o] = sum_i h[n][i]*b[i*C+o].  One thread per (node, f*C+o).
// sW_t layout [i][f*C+o]: lane x reads word i*120+x -> 64 lanes cover all 32
// banks 2-way (free).
template <int IN_C, int NPB>
__global__ void tmat_kernel(const float* __restrict__ h,   // [N][IN_C]
                            const float* __restrict__ W,   // [4][IN_C*C]
                            const float* __restrict__ b,   // [IN_C*C]
                            float* __restrict__ T) {       // [N][TW]
    __shared__ float sW_t[IN_C * TW];
    __shared__ float sh[NPB][IN_C];

    const int tid = threadIdx.x + threadIdx.y * TW;
    const int nthr = TW * NPB;
    for (int idx = tid; idx < IN_C * TW; idx += nthr) {
        const int i = idx / TW;
        const int x = idx - i * TW;
        const int f = x / C;
        const int o = x - f * C;
        sW_t[idx] = (f < 4) ? W[f * IN_C * C + i * C + o] : b[i * C + o];
    }
    const int n = blockIdx.x * NPB + threadIdx.y;
    if (n < N_NODES && threadIdx.x < IN_C)
        sh[threadIdx.y][threadIdx.x] = h[n * IN_C + threadIdx.x];
    __syncthreads();
    if (n >= N_NODES) return;

    const int x = threadIdx.x;
    float acc = 0.f;
#pragma unroll
    for (int i = 0; i < IN_C; ++i)
        acc = fmaf(sh[threadIdx.y][i], sW_t[i * TW + x], acc);
    T[n * TW + x] = acc;
}

// Per (edge, out_channel): msg = T4[src][o] + sum_f ea[f]*Tf[src][o];
// atomicMax into agg.  5 coalesced L2 loads + 4 FMA + 1 atomic per thread.
template <int EPB>
__global__ void edge2_kernel(const float* __restrict__ T,   // [N][TW]
                             const float* __restrict__ ea,  // [E][4]
                             const int* __restrict__ src,
                             const int* __restrict__ dst,
                             unsigned* __restrict__ agg) {
    __shared__ float s_ea[EPB][4];
    __shared__ int   s_sd[EPB][2];

    const int e = blockIdx.x * EPB + threadIdx.y;
    if (e < N_EDGES) {
        if (threadIdx.x < 4)  s_ea[threadIdx.y][threadIdx.x] = ea[e * 4 + threadIdx.x];
        if (threadIdx.x == 4) s_sd[threadIdx.y][0] = src[e];
        if (threadIdx.x == 5) s_sd[threadIdx.y][1] = dst[e];
    }
    __syncthreads();
    if (e >= N_EDGES) return;

    const int o = threadIdx.x;
    const float* Tr = T + (size_t)s_sd[threadIdx.y][0] * TW;
    float m = Tr[4 * C + o];
    m = fmaf(s_ea[threadIdx.y][0], Tr[0 * C + o], m);
    m = fmaf(s_ea[threadIdx.y][1], Tr[1 * C + o], m);
    m = fmaf(s_ea[threadIdx.y][2], Tr[2 * C + o], m);
    m = fmaf(s_ea[threadIdx.y][3], Tr[3 * C + o], m);
    atomicMax(&agg[s_sd[threadIdx.y][1] * C + o], fenc(m));
}

// Per (node, out_channel): h_out = relu6(agg_or_0 + h_in @ root + bias).
// Resets agg to 0 (each element exactly once -> clean for next layer).
template <int IN_C>
__global__ void node_kernel(const float* __restrict__ h_in,
                            unsigned* __restrict__ agg,
                            const float* __restrict__ root,  // [IN_C][C]
                            const float* __restrict__ bias,  // [C]
                            float* __restrict__ h_out) {
    const int t = blockIdx.x * blockDim.x + threadIdx.x;
    if (t >= N_NODES * C) return;
    const int n = t / C;
    const int o = t - n * C;
    const unsigned u = agg[t];
    agg[t] = 0u;
    float acc = (u == 0u ? 0.f : fdec(u)) + bias[o];
#pragma unroll
    for (int i = 0; i < IN_C; ++i)
        acc = fmaf(h_in[n * IN_C + i], root[i * C + o], acc);
    h_out[t] = fminf(fmaxf(acc, 0.f), 6.f);
}

// Stage 1 of head GEMV: per-block partials for 16 hidden units (deterministic).
__global__ void head1_kernel(const float* __restrict__ h,     // [N*C]
                             const float* __restrict__ w1,    // [N*C][HID]
                             float* __restrict__ partial) {   // [NB_HEAD][HID]
    __shared__ float s[256 * HID];
    float acc[HID];
#pragma unroll
    for (int j = 0; j < HID; ++j) acc[j] = 0.f;

    for (int k = blockIdx.x * blockDim.x + threadIdx.x; k < N_NODES * C;
         k += gridDim.x * blockDim.x) {
        const float f = h[k];
        const float4* wp = (const float4*)(w1 + (size_t)k * HID);
#pragma unroll
        for (int q = 0; q < 4; ++q) {
            const float4 w = wp[q];
            acc[q * 4 + 0] = fmaf(f, w.x, acc[q * 4 + 0]);
            acc[q * 4 + 1] = fmaf(f, w.y, acc[q * 4 + 1]);
            acc[q * 4 + 2] = fmaf(f, w.z, acc[q * 4 + 2]);
            acc[q * 4 + 3] = fmaf(f, w.w, acc[q * 4 + 3]);
        }
    }
#pragma unroll
    for (int j = 0; j < HID; ++j) s[threadIdx.x * HID + j] = acc[j];
    __syncthreads();
    for (int off = 128; off > 0; off >>= 1) {
        if (threadIdx.x < off) {
#pragma unroll
            for (int j = 0; j < HID; ++j)
                s[threadIdx.x * HID + j] += s[(threadIdx.x + off) * HID + j];
        }
        __syncthreads();
    }
    if (threadIdx.x < HID) partial[blockIdx.x * HID + threadIdx.x] = s[threadIdx.x];
}

// Stage 2: reduce partials in fixed order, ELU, 16-dot, ELU -> scalar out.
__global__ void head2_kernel(const float* __restrict__ partial,
                             const float* __restrict__ b1,
                             const float* __restrict__ w2,
                             const float* __restrict__ b2,
                             float* __restrict__ out) {
    __shared__ float hid[HID];
    const int j = threadIdx.x;
    if (j < HID) {
        float a = b1[j];
        for (int bidx = 0; bidx < NB_HEAD; ++bidx) a += partial[bidx * HID + j];
        hid[j] = (a > 0.f) ? a : expm1f(a);
    }
    __syncthreads();
    if (j == 0) {
        float a = b2[0];
#pragma unroll
        for (int q = 0; q < HID; ++q) a += hid[q] * w2[q];
        out[0] = (a > 0.f) ? a : expm1f(a);
    }
}

extern "C" void kernel_launch(void* const* d_in, const int* in_sizes, int n_in,
                              void* d_out, int out_size, void* d_ws, size_t ws_size,
                              hipStream_t stream) {
    const float* x      = (const float*)d_in[0];   // [N][FNODE]
    const float* ea     = (const float*)d_in[1];   // [E][FEDGE]
    const int*   ei     = (const int*)d_in[2];     // [2][E]
    const float* few    = (const float*)d_in[3];   // [FEDGE][FNODE*C]
    const float* feb    = (const float*)d_in[4];   // [FNODE*C]
    const float* ew     = (const float*)d_in[5];   // [FEDGE][C*C]
    const float* ebias  = (const float*)d_in[6];   // [C*C]
    const float* root0  = (const float*)d_in[7];   // [FNODE][C]
    const float* bias0  = (const float*)d_in[8];   // [C]
    const float* roots  = (const float*)d_in[9];   // [NITER][C][C]
    const float* biases = (const float*)d_in[10];  // [NITER][C]
    const float* w1     = (const float*)d_in[11];  // [N*C][HID]
    const float* b1     = (const float*)d_in[12];  // [HID]
    const float* w2     = (const float*)d_in[13];  // [HID]
    const float* b2     = (const float*)d_in[14];  // [1]
    float* out = (float*)d_out;

    const int* src = ei;
    const int* dst = ei + N_EDGES;

    void *pA_, *pB_, *pAgg_, *pT_, *pPart_;
    hipGetSymbolAddress(&pA_,   HIP_SYMBOL(g_hA));
    hipGetSymbolAddress(&pB_,   HIP_SYMBOL(g_hB));
    hipGetSymbolAddress(&pAgg_, HIP_SYMBOL(g_agg));
    hipGetSymbolAddress(&pT_,   HIP_SYMBOL(g_T));
    hipGetSymbolAddress(&pPart_,HIP_SYMBOL(g_partial));
    float*    hA      = (float*)pA_;
    float*    hB      = (float*)pB_;
    unsigned* agg     = (unsigned*)pAgg_;
    float*    T       = (float*)pT_;
    float*    partial = (float*)pPart_;

    constexpr int EPB = 32;
    constexpr int NPB = 8;
    dim3 eblk(C, EPB);
    dim3 tblk(TW, NPB);
    const int egrid = (N_EDGES + EPB - 1) / EPB;
    const int tgrid = (N_NODES + NPB - 1) / NPB;
    const int ngrid = (N_NODES * C + 255) / 256;

    zero_agg_kernel<<<ngrid, 256, 0, stream>>>();

    // Layer 0: x [N,8] -> hA [N,24]
    tmat_kernel<FNODE, NPB><<<tgrid, tblk, 0, stream>>>(x, few, feb, T);
    edge2_kernel<EPB><<<egrid, eblk, 0, stream>>>(T, ea, src, dst, agg);
    node_kernel<FNODE><<<ngrid, 256, 0, stream>>>(x, agg, root0, bias0, hA);

    float* cur = hA;
    float* nxt = hB;
    for (int i = 0; i < NITER; ++i) {
        tmat_kernel<C, NPB><<<tgrid, tblk, 0, stream>>>(cur, ew, ebias, T);
        edge2_kernel<EPB><<<egrid, eblk, 0, stream>>>(T, ea, src, dst, agg);
        node_kernel<C><<<ngrid, 256, 0, stream>>>(cur, agg, roots + i * C * C,
                                                  biases + i * C, nxt);
        float* t = cur; cur = nxt; nxt = t;
    }

    head1_kernel<<<NB_HEAD, 256, 0, stream>>>(cur, w1, partial);
    head2_kernel<<<1, 64, 0, stream>>>(partial, b1, w2, b2, out);
}